// Round 5
// baseline (203.592 us; speedup 1.0000x reference)
//
#include <hip/hip_runtime.h>

#define K_DIM 4096
#define N_DIM 4096
#define NT (K_DIM / 64)  // 64 K-tiles, 64 bytes deep each

typedef int v4i __attribute__((ext_vector_type(4)));
typedef int v16i __attribute__((ext_vector_type(16)));

__device__ __forceinline__ void gload_lds16(const void* g, void* l) {
  __builtin_amdgcn_global_load_lds(
      (const __attribute__((address_space(1))) void*)g,
      (__attribute__((address_space(3))) void*)l, 16, 0, 0);
}

__device__ __forceinline__ int pack4(int4 w) {
  return (w.x & 0xff) | ((w.y & 0xff) << 8) | ((w.z & 0xff) << 16) | (w.w << 24);
}

// int32 -> int8 pack, 16 elements per thread
__global__ __launch_bounds__(256) void pack_kernel(const int* __restrict__ src,
                                                   int4* __restrict__ dst, int n16) {
  int i = blockIdx.x * 256 + threadIdx.x;
  if (i >= n16) return;
  const int4* s = (const int4*)src + (size_t)i * 4;
  int4 w0 = s[0], w1 = s[1], w2 = s[2], w3 = s[3];
  int4 r;
  r.x = pack4(w0); r.y = pack4(w1); r.z = pack4(w2); r.w = pack4(w3);
  dst[i] = r;
}

// 256x256 tile, BK=64 bytes, 8 waves (2M x 4N), mfma_i32_32x32x32_i8.
// 4-slot circular LDS; staged 3 tiles ahead; ONE barrier per tile with
// counted vmcnt(4) (never 0 mid-loop). RACE DISCIPLINE (m201): every
// wave's ds_reads are fully drained (lgkmcnt(0)) BEFORE its barrier
// arrival -- no LDS read is ever outstanding across a barrier. Slot
// reuse is then safe: stage(kt+3) writes slot (kt-1)&3, whose reads all
// completed before the end-of-(kt-1) barrier that precedes the stage.
// LDS swizzle: slot(r,c) holds global 16B-chunk c ^ ((r>>1)&3); inverse
// applied on the global SOURCE (linear LDS dest), same XOR on ds_read.
__global__ __launch_bounds__(512, 2) void gemm256(
    const char* __restrict__ Ap, const char* __restrict__ Bp,
    const int* __restrict__ bias, const float* __restrict__ pa,
    const float* __restrict__ pb, int* __restrict__ out) {
  extern __shared__ __align__(16) char lds[];  // 131072 bytes

  const int tid = threadIdx.x;
  const int wid = tid >> 6;
  const int lane = tid & 63;

  // XCD-aware bijective swizzle (nwg = 512, % 8 == 0)
  const int nwg = gridDim.x;
  const int cpx = nwg >> 3;
  const int flat = blockIdx.x;
  const int wg = (flat & 7) * cpx + (flat >> 3);
  const int br = wg >> 4;  // 0..31
  const int bn = wg & 15;  // 0..15

  const int wr = wid >> 2;   // 0..1 -> M half (128 rows)
  const int wcol = wid & 3;  // 0..3 -> N quarter (64 cols)

  // --- staging (per-lane global src, wave-uniform linear LDS dest) ---
  const int srow = tid >> 2;                        // 0..127
  const int schunk = (tid & 3) ^ ((tid >> 3) & 3);  // inverse-swizzled chunk
  const char* aSrc = Ap + (size_t)(br * 256 + srow) * K_DIM + schunk * 16;
  const char* bSrc = Bp + (size_t)(bn * 256 + srow) * K_DIM + schunk * 16;

  auto stage = [&](int kt) {
    const char* sa = aSrc + kt * 64;
    const char* sb2 = bSrc + kt * 64;
    char* da = lds + (kt & 3) * 16384 + wid * 1024;
    char* db = lds + 65536 + (kt & 3) * 16384 + wid * 1024;
    gload_lds16(sa, da);
    gload_lds16(sa + (size_t)128 * K_DIM, da + 8192);
    gload_lds16(sb2, db);
    gload_lds16(sb2 + (size_t)128 * K_DIM, db + 8192);
  };

  // --- fragment read addressing (32x32x32: row = lane&31, k16 = lane>>5) ---
  const int lrow = lane & 31;
  const int hi = lane >> 5;
  const int swz = (lrow >> 1) & 3;
  const int kOff0 = (hi ^ swz) << 4;  // ks=0 swizzled byte offset
  const int kOff1 = kOff0 ^ 32;       // ks=1
  const int aBase = (wr * 128 + lrow) * 64;           // + mi*2048 + slot*16384
  const int bBase = 65536 + (wcol * 64 + lrow) * 64;  // + ni*2048 + slot*16384

  v16i acc[4][2];
  {
    v16i z = {0};
#pragma unroll
    for (int mi = 0; mi < 4; ++mi)
#pragma unroll
      for (int ni = 0; ni < 2; ++ni) acc[mi][ni] = z;
  }

  // prologue: stage tiles 0,1,2; need only tile 0 resident at first reads
  stage(0); stage(1); stage(2);
  asm volatile("s_waitcnt vmcnt(8)" ::: "memory");
  __builtin_amdgcn_s_barrier();

  for (int kt = 0; kt < NT; ++kt) {
    const int sb = (kt & 3) * 16384;

    // all 12 fragment reads for this tile, ks=0 batch first
    v4i a0[4], b0[2], a1[4], b1[2];
#pragma unroll
    for (int mi = 0; mi < 4; ++mi) a0[mi] = *(const v4i*)&lds[sb + aBase + mi * 2048 + kOff0];
#pragma unroll
    for (int ni = 0; ni < 2; ++ni) b0[ni] = *(const v4i*)&lds[sb + bBase + ni * 2048 + kOff0];
#pragma unroll
    for (int mi = 0; mi < 4; ++mi) a1[mi] = *(const v4i*)&lds[sb + aBase + mi * 2048 + kOff1];
#pragma unroll
    for (int ni = 0; ni < 2; ++ni) b1[ni] = *(const v4i*)&lds[sb + bBase + ni * 2048 + kOff1];

    if (kt + 3 < NT) stage(kt + 3);  // slot (kt-1)&3: fully read before prev barrier

    // ks=0: wait only the first 6 reads (6 newest = ks=1 batch outstanding)
    asm volatile("s_waitcnt lgkmcnt(6)" ::: "memory");
    __builtin_amdgcn_sched_barrier(0);
    __builtin_amdgcn_s_setprio(1);
#pragma unroll
    for (int mi = 0; mi < 4; ++mi)
#pragma unroll
      for (int ni = 0; ni < 2; ++ni)
        acc[mi][ni] =
            __builtin_amdgcn_mfma_i32_32x32x32_i8(a0[mi], b0[ni], acc[mi][ni], 0, 0, 0);
    __builtin_amdgcn_s_setprio(0);

    // ks=1: full drain -> NO ds_read outstanding past this point
    asm volatile("s_waitcnt lgkmcnt(0)" ::: "memory");
    __builtin_amdgcn_sched_barrier(0);
    __builtin_amdgcn_s_setprio(1);
#pragma unroll
    for (int mi = 0; mi < 4; ++mi)
#pragma unroll
      for (int ni = 0; ni < 2; ++ni)
        acc[mi][ni] =
            __builtin_amdgcn_mfma_i32_32x32x32_i8(a1[mi], b1[ni], acc[mi][ni], 0, 0, 0);
    __builtin_amdgcn_s_setprio(0);

    // tile boundary: next tile's data landed for all waves + slot-reuse fence
    if (kt < NT - 3)
      asm volatile("s_waitcnt vmcnt(4)" ::: "memory");
    else
      asm volatile("s_waitcnt vmcnt(0)" ::: "memory");
    __builtin_amdgcn_s_barrier();
  }

  // epilogue: y = round(alpha*acc + beta*bias), clamp, write int32
  const float alpha = *pa;
  const float beta = *pb;
#pragma unroll
  for (int ni = 0; ni < 2; ++ni) {
    const int n = bn * 256 + wcol * 64 + ni * 32 + lrow;
    const float bb = __fmul_rn(beta, (float)bias[n]);
#pragma unroll
    for (int mi = 0; mi < 4; ++mi) {
#pragma unroll
      for (int r = 0; r < 16; ++r) {
        const int row = (r & 3) + 8 * (r >> 2) + 4 * hi;
        const int m = br * 256 + wr * 128 + mi * 32 + row;
        float y = __fadd_rn(__fmul_rn(alpha, (float)acc[mi][ni][r]), bb);
        y = rintf(y);
        y = fminf(127.f, fmaxf(-128.f, y));
        out[(size_t)m * N_DIM + n] = (int)y;
      }
    }
  }
}

extern "C" void kernel_launch(void* const* d_in, const int* in_sizes, int n_in,
                              void* d_out, int out_size, void* d_ws, size_t ws_size,
                              hipStream_t stream) {
  const int* x = (const int*)d_in[0];       // [M,K] int8 values in int32
  const int* w = (const int*)d_in[1];       // [N,K] int8 values in int32
  const int* bias = (const int*)d_in[2];    // [N] int8 values in int32
  const float* pa = (const float*)d_in[3];  // alpha
  const float* pb = (const float*)d_in[4];  // beta
  int* out = (int*)d_out;

  const int M = in_sizes[0] / K_DIM;  // 8192
  const size_t xBytes = (size_t)M * K_DIM;
  const size_t wBytes = (size_t)N_DIM * K_DIM;

  char* xp = (char*)d_ws;
  char* wp = xp + xBytes;
  const int n16x = (int)(xBytes / 16);
  const int n16w = (int)(wBytes / 16);
  pack_kernel<<<(n16x + 255) / 256, 256, 0, stream>>>(x, (int4*)xp, n16x);
  pack_kernel<<<(n16w + 255) / 256, 256, 0, stream>>>(w, (int4*)wp, n16w);

  const int nwg = (M / 256) * (N_DIM / 256);  // 512
  hipFuncSetAttribute((const void*)gemm256,
                      hipFuncAttributeMaxDynamicSharedMemorySize, 131072);
  gemm256<<<nwg, 512, 131072, stream>>>(xp, wp, bias, pa, pb, out);
}

// Round 6
// 197.807 us; speedup vs baseline: 1.0292x; 1.0292x over previous
//
#include <hip/hip_runtime.h>

#define K_DIM 4096
#define N_DIM 4096
#define NT (K_DIM / 128)  // 32 K-tiles, 128 bytes deep

typedef int v4i __attribute__((ext_vector_type(4)));
typedef int v16i __attribute__((ext_vector_type(16)));

__device__ __forceinline__ void gload_lds16(const void* g, void* l) {
  __builtin_amdgcn_global_load_lds(
      (const __attribute__((address_space(1))) void*)g,
      (__attribute__((address_space(3))) void*)l, 16, 0, 0);
}

__device__ __forceinline__ int pack4(int4 w) {
  return (w.x & 0xff) | ((w.y & 0xff) << 8) | ((w.z & 0xff) << 16) | (w.w << 24);
}

// int32 -> int8 pack, 16 elements per thread
__global__ __launch_bounds__(256) void pack_kernel(const int* __restrict__ src,
                                                   int4* __restrict__ dst, int n16) {
  int i = blockIdx.x * 256 + threadIdx.x;
  if (i >= n16) return;
  const int4* s = (const int4*)src + (size_t)i * 4;
  int4 w0 = s[0], w1 = s[1], w2 = s[2], w3 = s[3];
  int4 r;
  r.x = pack4(w0); r.y = pack4(w1); r.z = pack4(w2); r.w = pack4(w3);
  dst[i] = r;
}

// 256x256 tile, BK=128 bytes, 8 waves (2M x 4N), mfma_i32_32x32x32_i8.
// 2-slot double-buffered LDS (2 x 64KB). 128-BYTE LDS ROWS with the
// r3-validated conflict-free swizzle: slot(r,c) holds global chunk
// c ^ (r&7); inverse applied on the global SOURCE (linear LDS dest
// required by global_load_lds), same XOR on ds_read.
// ONE barrier per tile: stage(kt+1) issued at tile TOP (~1400cy before
// the boundary vmcnt(0), so the drain is latency-covered); tile interior
// is barrier-free so the 2 waves/SIMD desync and hide each other's LDS
// latency. Race discipline (r5): every ds_read drains (lgkmcnt(0))
// before the wave's barrier arrival.
__global__ __launch_bounds__(512, 2) void gemm256(
    const char* __restrict__ Ap, const char* __restrict__ Bp,
    const int* __restrict__ bias, const float* __restrict__ pa,
    const float* __restrict__ pb, int* __restrict__ out) {
  extern __shared__ __align__(16) char lds[];  // 131072 bytes

  const int tid = threadIdx.x;
  const int wid = tid >> 6;
  const int lane = tid & 63;

  // XCD-aware bijective swizzle (nwg = 512, % 8 == 0)
  const int nwg = gridDim.x;
  const int cpx = nwg >> 3;
  const int flat = blockIdx.x;
  const int wg = (flat & 7) * cpx + (flat >> 3);
  const int br = wg >> 4;  // 0..31
  const int bn = wg & 15;  // 0..15

  const int wr = wid >> 2;   // 0..1 -> M half (128 rows)
  const int wcol = wid & 3;  // 0..3 -> N quarter (64 cols)

  // --- staging: thread t -> LDS byte j*8192 + t*16 (linear, wave-uniform
  // base + lane*16) = row j*64 + (t>>3), stored chunk t&7; source chunk
  // (t&7) ^ ((t>>3)&7)  [inverse of read-side XOR]
  const int srow = tid >> 3;                        // 0..63
  const int schunk = (tid & 7) ^ (srow & 7);        // inverse-swizzled chunk
  const char* aSrc = Ap + (size_t)(br * 256 + srow) * K_DIM + schunk * 16;
  const char* bSrc = Bp + (size_t)(bn * 256 + srow) * K_DIM + schunk * 16;
  char* const dA = lds + tid * 16;           // + slot*32768 + j*8192
  char* const dB = lds + 65536 + tid * 16;

  auto stage = [&](int kt) {
    const int s = (kt & 1) * 32768;
    const char* sa = aSrc + kt * 128;
    const char* sbp = bSrc + kt * 128;
#pragma unroll
    for (int j = 0; j < 4; ++j) {
      gload_lds16(sa + (size_t)j * 64 * K_DIM, dA + s + j * 8192);
      gload_lds16(sbp + (size_t)j * 64 * K_DIM, dB + s + j * 8192);
    }
  };

  // --- fragment reads (32x32x32: row = lane&31, 16B k-chunk = lane>>5) ---
  // k-step ks needs global chunk 2*ks + hi at row r -> stored position
  // (2*ks + hi) ^ (r&7); r&7 == lrow&7 (all row offsets are mult. of 32)
  const int lrow = lane & 31;
  const int hi = lane >> 5;
  const int aBase = (wr * 128 + lrow) * 128;           // + slot + mi*4096 + pos
  const int bBase = 65536 + (wcol * 64 + lrow) * 128;  // + slot + ni*4096 + pos
  const int p0 = ((0 + hi) ^ (lrow & 7)) << 4;
  const int p1 = ((2 + hi) ^ (lrow & 7)) << 4;
  const int p2 = ((4 + hi) ^ (lrow & 7)) << 4;
  const int p3 = ((6 + hi) ^ (lrow & 7)) << 4;

  v16i acc[4][2];
  {
    v16i z = {0};
#pragma unroll
    for (int mi = 0; mi < 4; ++mi)
#pragma unroll
      for (int ni = 0; ni < 2; ++ni) acc[mi][ni] = z;
  }

  // prologue
  stage(0);
  asm volatile("s_waitcnt vmcnt(0)" ::: "memory");
  __builtin_amdgcn_s_barrier();

  for (int kt = 0; kt < NT; ++kt) {
    const int sb = (kt & 1) * 32768;
    if (kt + 1 < NT) stage(kt + 1);  // other slot; boundary-covered

    v4i a0[4], b0[2], a1[4], b1[2];
    // ks = 0,1
#pragma unroll
    for (int mi = 0; mi < 4; ++mi) a0[mi] = *(const v4i*)&lds[sb + aBase + mi * 4096 + p0];
#pragma unroll
    for (int ni = 0; ni < 2; ++ni) b0[ni] = *(const v4i*)&lds[sb + bBase + ni * 4096 + p0];
#pragma unroll
    for (int mi = 0; mi < 4; ++mi) a1[mi] = *(const v4i*)&lds[sb + aBase + mi * 4096 + p1];
#pragma unroll
    for (int ni = 0; ni < 2; ++ni) b1[ni] = *(const v4i*)&lds[sb + bBase + ni * 4096 + p1];

    asm volatile("s_waitcnt lgkmcnt(6)" ::: "memory");
    __builtin_amdgcn_sched_barrier(0);
    __builtin_amdgcn_s_setprio(1);
#pragma unroll
    for (int mi = 0; mi < 4; ++mi)
#pragma unroll
      for (int ni = 0; ni < 2; ++ni)
        acc[mi][ni] =
            __builtin_amdgcn_mfma_i32_32x32x32_i8(a0[mi], b0[ni], acc[mi][ni], 0, 0, 0);
    __builtin_amdgcn_s_setprio(0);

    asm volatile("s_waitcnt lgkmcnt(0)" ::: "memory");
    __builtin_amdgcn_sched_barrier(0);
    __builtin_amdgcn_s_setprio(1);
#pragma unroll
    for (int mi = 0; mi < 4; ++mi)
#pragma unroll
      for (int ni = 0; ni < 2; ++ni)
        acc[mi][ni] =
            __builtin_amdgcn_mfma_i32_32x32x32_i8(a1[mi], b1[ni], acc[mi][ni], 0, 0, 0);
    __builtin_amdgcn_s_setprio(0);

    // ks = 2,3
#pragma unroll
    for (int mi = 0; mi < 4; ++mi) a0[mi] = *(const v4i*)&lds[sb + aBase + mi * 4096 + p2];
#pragma unroll
    for (int ni = 0; ni < 2; ++ni) b0[ni] = *(const v4i*)&lds[sb + bBase + ni * 4096 + p2];
#pragma unroll
    for (int mi = 0; mi < 4; ++mi) a1[mi] = *(const v4i*)&lds[sb + aBase + mi * 4096 + p3];
#pragma unroll
    for (int ni = 0; ni < 2; ++ni) b1[ni] = *(const v4i*)&lds[sb + bBase + ni * 4096 + p3];

    asm volatile("s_waitcnt lgkmcnt(6)" ::: "memory");
    __builtin_amdgcn_sched_barrier(0);
    __builtin_amdgcn_s_setprio(1);
#pragma unroll
    for (int mi = 0; mi < 4; ++mi)
#pragma unroll
      for (int ni = 0; ni < 2; ++ni)
        acc[mi][ni] =
            __builtin_amdgcn_mfma_i32_32x32x32_i8(a0[mi], b0[ni], acc[mi][ni], 0, 0, 0);
    __builtin_amdgcn_s_setprio(0);

    asm volatile("s_waitcnt lgkmcnt(0)" ::: "memory");
    __builtin_amdgcn_sched_barrier(0);
    __builtin_amdgcn_s_setprio(1);
#pragma unroll
    for (int mi = 0; mi < 4; ++mi)
#pragma unroll
      for (int ni = 0; ni < 2; ++ni)
        acc[mi][ni] =
            __builtin_amdgcn_mfma_i32_32x32x32_i8(a1[mi], b1[ni], acc[mi][ni], 0, 0, 0);
    __builtin_amdgcn_s_setprio(0);

    // tile boundary: stage(kt+1) resident for all waves + slot-reuse fence
    if (kt + 1 < NT) {
      asm volatile("s_waitcnt vmcnt(0)" ::: "memory");
      __builtin_amdgcn_s_barrier();
    }
  }

  // epilogue: y = round(alpha*acc + beta*bias), clamp, write int32
  const float alpha = *pa;
  const float beta = *pb;
#pragma unroll
  for (int ni = 0; ni < 2; ++ni) {
    const int n = bn * 256 + wcol * 64 + ni * 32 + lrow;
    const float bb = __fmul_rn(beta, (float)bias[n]);
#pragma unroll
    for (int mi = 0; mi < 4; ++mi) {
#pragma unroll
      for (int r = 0; r < 16; ++r) {
        const int row = (r & 3) + 8 * (r >> 2) + 4 * hi;
        const int m = br * 256 + wr * 128 + mi * 32 + row;
        float y = __fadd_rn(__fmul_rn(alpha, (float)acc[mi][ni][r]), bb);
        y = rintf(y);
        y = fminf(127.f, fmaxf(-128.f, y));
        out[(size_t)m * N_DIM + n] = (int)y;
      }
    }
  }
}

extern "C" void kernel_launch(void* const* d_in, const int* in_sizes, int n_in,
                              void* d_out, int out_size, void* d_ws, size_t ws_size,
                              hipStream_t stream) {
  const int* x = (const int*)d_in[0];       // [M,K] int8 values in int32
  const int* w = (const int*)d_in[1];       // [N,K] int8 values in int32
  const int* bias = (const int*)d_in[2];    // [N] int8 values in int32
  const float* pa = (const float*)d_in[3];  // alpha
  const float* pb = (const float*)d_in[4];  // beta
  int* out = (int*)d_out;

  const int M = in_sizes[0] / K_DIM;  // 8192
  const size_t xBytes = (size_t)M * K_DIM;
  const size_t wBytes = (size_t)N_DIM * K_DIM;

  char* xp = (char*)d_ws;
  char* wp = xp + xBytes;
  const int n16x = (int)(xBytes / 16);
  const int n16w = (int)(wBytes / 16);
  pack_kernel<<<(n16x + 255) / 256, 256, 0, stream>>>(x, (int4*)xp, n16x);
  pack_kernel<<<(n16w + 255) / 256, 256, 0, stream>>>(w, (int4*)wp, n16w);

  const int nwg = (M / 256) * (N_DIM / 256);  // 512
  hipFuncSetAttribute((const void*)gemm256,
                      hipFuncAttributeMaxDynamicSharedMemorySize, 131072);
  gemm256<<<nwg, 512, 131072, stream>>>(xp, wp, bias, pa, pb, out);
}

// Round 7
// 191.160 us; speedup vs baseline: 1.0650x; 1.0348x over previous
//
#include <hip/hip_runtime.h>

#define K_DIM 4096
#define N_DIM 4096
#define NT (K_DIM / 128)  // 32 K-tiles, 128 bytes deep

typedef int v4i __attribute__((ext_vector_type(4)));

__device__ __forceinline__ void gload_lds16(const void* g, void* l) {
  __builtin_amdgcn_global_load_lds(
      (const __attribute__((address_space(1))) void*)g,
      (__attribute__((address_space(3))) void*)l, 16, 0, 0);
}

__device__ __forceinline__ int pack4(int4 w) {
  return (w.x & 0xff) | ((w.y & 0xff) << 8) | ((w.z & 0xff) << 16) | (w.w << 24);
}

// int32 -> int8 pack, 16 elements per thread
__global__ __launch_bounds__(256) void pack_kernel(const int* __restrict__ src,
                                                   int4* __restrict__ dst, int n16) {
  int i = blockIdx.x * 256 + threadIdx.x;
  if (i >= n16) return;
  const int4* s = (const int4*)src + (size_t)i * 4;
  int4 w0 = s[0], w1 = s[1], w2 = s[2], w3 = s[3];
  int4 r;
  r.x = pack4(w0); r.y = pack4(w1); r.z = pack4(w2); r.w = pack4(w3);
  dst[i] = r;
}

// m201-style 8-phase schedule ported to i8:
// 256x256 tile, BK=128 bytes, 8 waves (2M x 4N, wave tile 128x64),
// mfma_i32_16x16x64_i8 (the fragment-read pattern MEASURED conflict-free
// in r2/r3; the 32x32 pattern measured 1.26e7 conflict-cycles).
// LDS: 2 dbuf x (A 256x128B + B 256x128B) = 128 KB.
// Per K-tile: 4 phases, each {ds-read subtile -> stage gloads -> s_barrier
// -> lgkmcnt(0) -> setprio(1) -> 16 MFMA -> setprio(0) -> s_barrier}.
// The barrier pair per phase forces the 2 waves/SIMD into alternating
// load/MFMA roles (T3; T5 setprio then arbitrates). vmcnt(0) once per
// tile at ph4 -- newest outstanding stage is 2-3 phases old, so the wait
// is latency-covered (not m218's harmful per-phase drain).
// Race discipline: every ds_read drains (lgkmcnt(0)) before its phase-end
// barrier; stage(kt+1) writes the opposite dbuf, whose prior readers all
// drained >=2 barriers before the stage issue.
__global__ __launch_bounds__(512, 2) void gemm256(
    const char* __restrict__ Ap, const char* __restrict__ Bp,
    const int* __restrict__ bias, const float* __restrict__ pa,
    const float* __restrict__ pb, int* __restrict__ out) {
  extern __shared__ __align__(16) char lds[];  // 131072 bytes

  const int tid = threadIdx.x;
  const int wid = tid >> 6;
  const int lane = tid & 63;

  // XCD-aware bijective swizzle (nwg = 512, % 8 == 0)
  const int nwg = gridDim.x;
  const int cpx = nwg >> 3;
  const int flat = blockIdx.x;
  const int wg = (flat & 7) * cpx + (flat >> 3);
  const int br = wg >> 4;  // 0..31
  const int bn = wg & 15;  // 0..15

  const int wr = wid >> 2;   // 0..1 -> M half (128 rows)
  const int wcol = wid & 3;  // 0..3 -> N quarter (64 cols)

  // --- staging: thread t -> LDS row j*64 + (t>>3), stored chunk t&7;
  // source chunk (t&7)^((t>>3)&7)  [inverse of read-side XOR c^(r&7)]
  const int srow = tid >> 3;                  // 0..63
  const int schunk = (tid & 7) ^ (srow & 7);  // inverse-swizzled chunk
  const char* aSrc = Ap + (size_t)(br * 256 + srow) * K_DIM + schunk * 16;
  const char* bSrc = Bp + (size_t)(bn * 256 + srow) * K_DIM + schunk * 16;
  char* const dA = lds + tid * 16;           // + dbuf*32768 + j*8192
  char* const dB = lds + 65536 + tid * 16;

  auto stageA = [&](int kt) {
    const int s = (kt & 1) * 32768;
    const char* sa = aSrc + kt * 128;
#pragma unroll
    for (int j = 0; j < 4; ++j)
      gload_lds16(sa + (size_t)j * 64 * K_DIM, dA + s + j * 8192);
  };
  auto stageB = [&](int kt) {
    const int s = (kt & 1) * 32768;
    const char* sbp = bSrc + kt * 128;
#pragma unroll
    for (int j = 0; j < 4; ++j)
      gload_lds16(sbp + (size_t)j * 64 * K_DIM, dB + s + j * 8192);
  };

  // --- fragment reads (16x16x64, r2-verbatim: row = lane&15, g = lane>>4;
  // k-chunk ks*4+g at row r lives at stored position (ks*4+g)^(r&7);
  // r&7 == lrow&7 for all frag rows) ---
  const int lrow = lane & 15;
  const int g = lane >> 4;
  const int pos0 = ((g ^ (lrow & 7)) << 4);  // ks=0
  const int pos1 = pos0 ^ 64;                // ks=1 (chunk 4+g)
  const int aBase = (wr * 128 + lrow) * 128;           // + dbuf + mi*2048 + pos
  const int bBase = 65536 + (wcol * 64 + lrow) * 128;  // + dbuf + ni*2048 + pos

  v4i acc[8][4];
  {
    v4i z = {0, 0, 0, 0};
#pragma unroll
    for (int mi = 0; mi < 8; ++mi)
#pragma unroll
      for (int ni = 0; ni < 4; ++ni) acc[mi][ni] = z;
  }

  // prologue
  stageA(0);
  stageB(0);
  asm volatile("s_waitcnt vmcnt(0)" ::: "memory");
  __builtin_amdgcn_s_barrier();

  for (int kt = 0; kt < NT; ++kt) {
    const int d = (kt & 1) * 32768;
    v4i aL[4], aH[4], bb[4];

    // ---------- phase 1: A[0..3] ks0 + B[0..3] ks0 ----------
#pragma unroll
    for (int mi = 0; mi < 4; ++mi) aL[mi] = *(const v4i*)&lds[d + aBase + mi * 2048 + pos0];
#pragma unroll
    for (int ni = 0; ni < 4; ++ni) bb[ni] = *(const v4i*)&lds[d + bBase + ni * 2048 + pos0];
    if (kt + 1 < NT) stageA(kt + 1);
    __builtin_amdgcn_s_barrier();
    asm volatile("s_waitcnt lgkmcnt(0)" ::: "memory");
    __builtin_amdgcn_sched_barrier(0);
    __builtin_amdgcn_s_setprio(1);
#pragma unroll
    for (int mi = 0; mi < 4; ++mi)
#pragma unroll
      for (int ni = 0; ni < 4; ++ni)
        acc[mi][ni] =
            __builtin_amdgcn_mfma_i32_16x16x64_i8(aL[mi], bb[ni], acc[mi][ni], 0, 0, 0);
    __builtin_amdgcn_s_setprio(0);
    __builtin_amdgcn_s_barrier();

    // ---------- phase 2: A[4..7] ks0 (B reused in regs) ----------
#pragma unroll
    for (int mi = 0; mi < 4; ++mi)
      aH[mi] = *(const v4i*)&lds[d + aBase + (mi + 4) * 2048 + pos0];
    if (kt + 1 < NT) stageB(kt + 1);
    __builtin_amdgcn_s_barrier();
    asm volatile("s_waitcnt lgkmcnt(0)" ::: "memory");
    __builtin_amdgcn_sched_barrier(0);
    __builtin_amdgcn_s_setprio(1);
#pragma unroll
    for (int mi = 0; mi < 4; ++mi)
#pragma unroll
      for (int ni = 0; ni < 4; ++ni)
        acc[mi + 4][ni] =
            __builtin_amdgcn_mfma_i32_16x16x64_i8(aH[mi], bb[ni], acc[mi + 4][ni], 0, 0, 0);
    __builtin_amdgcn_s_setprio(0);
    __builtin_amdgcn_s_barrier();

    // ---------- phase 3: A[0..3] ks1 + B[0..3] ks1 ----------
#pragma unroll
    for (int mi = 0; mi < 4; ++mi) aL[mi] = *(const v4i*)&lds[d + aBase + mi * 2048 + pos1];
#pragma unroll
    for (int ni = 0; ni < 4; ++ni) bb[ni] = *(const v4i*)&lds[d + bBase + ni * 2048 + pos1];
    __builtin_amdgcn_s_barrier();
    asm volatile("s_waitcnt lgkmcnt(0)" ::: "memory");
    __builtin_amdgcn_sched_barrier(0);
    __builtin_amdgcn_s_setprio(1);
#pragma unroll
    for (int mi = 0; mi < 4; ++mi)
#pragma unroll
      for (int ni = 0; ni < 4; ++ni)
        acc[mi][ni] =
            __builtin_amdgcn_mfma_i32_16x16x64_i8(aL[mi], bb[ni], acc[mi][ni], 0, 0, 0);
    __builtin_amdgcn_s_setprio(0);
    __builtin_amdgcn_s_barrier();

    // ---------- phase 4: A[4..7] ks1 ----------
#pragma unroll
    for (int mi = 0; mi < 4; ++mi)
      aH[mi] = *(const v4i*)&lds[d + aBase + (mi + 4) * 2048 + pos1];
    // all of tile kt+1 resident (stages issued 2-3 phases ago -> ~free wait)
    asm volatile("s_waitcnt vmcnt(0)" ::: "memory");
    __builtin_amdgcn_s_barrier();
    asm volatile("s_waitcnt lgkmcnt(0)" ::: "memory");
    __builtin_amdgcn_sched_barrier(0);
    __builtin_amdgcn_s_setprio(1);
#pragma unroll
    for (int mi = 0; mi < 4; ++mi)
#pragma unroll
      for (int ni = 0; ni < 4; ++ni)
        acc[mi + 4][ni] =
            __builtin_amdgcn_mfma_i32_16x16x64_i8(aH[mi], bb[ni], acc[mi + 4][ni], 0, 0, 0);
    __builtin_amdgcn_s_setprio(0);
    __builtin_amdgcn_s_barrier();
  }

  // epilogue: y = round(alpha*acc + beta*bias), clamp, write int32
  const float alpha = *pa;
  const float beta = *pb;
  const int rg = lane >> 4;
#pragma unroll
  for (int ni = 0; ni < 4; ++ni) {
    const int n = bn * 256 + wcol * 64 + ni * 16 + lrow;
    const float bb2 = __fmul_rn(beta, (float)bias[n]);
#pragma unroll
    for (int mi = 0; mi < 8; ++mi) {
#pragma unroll
      for (int j = 0; j < 4; ++j) {
        const int m = br * 256 + wr * 128 + mi * 16 + rg * 4 + j;
        float y = __fadd_rn(__fmul_rn(alpha, (float)acc[mi][ni][j]), bb2);
        y = rintf(y);
        y = fminf(127.f, fmaxf(-128.f, y));
        out[(size_t)m * N_DIM + n] = (int)y;
      }
    }
  }
}

extern "C" void kernel_launch(void* const* d_in, const int* in_sizes, int n_in,
                              void* d_out, int out_size, void* d_ws, size_t ws_size,
                              hipStream_t stream) {
  const int* x = (const int*)d_in[0];       // [M,K] int8 values in int32
  const int* w = (const int*)d_in[1];       // [N,K] int8 values in int32
  const int* bias = (const int*)d_in[2];    // [N] int8 values in int32
  const float* pa = (const float*)d_in[3];  // alpha
  const float* pb = (const float*)d_in[4];  // beta
  int* out = (int*)d_out;

  const int M = in_sizes[0] / K_DIM;  // 8192
  const size_t xBytes = (size_t)M * K_DIM;
  const size_t wBytes = (size_t)N_DIM * K_DIM;

  char* xp = (char*)d_ws;
  char* wp = xp + xBytes;
  const int n16x = (int)(xBytes / 16);
  const int n16w = (int)(wBytes / 16);
  pack_kernel<<<(n16x + 255) / 256, 256, 0, stream>>>(x, (int4*)xp, n16x);
  pack_kernel<<<(n16w + 255) / 256, 256, 0, stream>>>(w, (int4*)wp, n16w);

  const int nwg = (M / 256) * (N_DIM / 256);  // 512
  hipFuncSetAttribute((const void*)gemm256,
                      hipFuncAttributeMaxDynamicSharedMemorySize, 131072);
  gemm256<<<nwg, 512, 131072, stream>>>(xp, wp, bias, pa, pb, out);
}